// Round 4
// baseline (190.356 us; speedup 1.0000x reference)
//
#include <hip/hip_runtime.h>
#include <math.h>

// Problem constants: B=2, S=2048, E=1024, NH=16, hd=64, T=1 (seq = S)
#define BB 2
#define SS 2048
#define EE 1024
#define NHH 16
#define HD 64
#define HD2 32

typedef _Float16 f16x8 __attribute__((ext_vector_type(8)));   // 8 f16 = 4 VGPRs
typedef __attribute__((ext_vector_type(4))) float f32x4;      // MFMA accumulator

// pack two fp32 -> half2 with RNE (v_cvt_f16_f32 x2 + pack)
static __device__ __forceinline__ unsigned pkh(float a, float b) {
    union { _Float16 h[2]; unsigned u; } v;
    v.h[0] = (_Float16)a; v.h[1] = (_Float16)b;
    return v.u;
}

// ---- async global->LDS DMA, 16B per lane (global_load_lds_dwordx4) ----
static __device__ __forceinline__ void dma16(const void* g, void* l) {
    __builtin_amdgcn_global_load_lds(
        (const __attribute__((address_space(1))) unsigned int*)g,
        (__attribute__((address_space(3))) unsigned int*)l,
        16, 0, 0);
}

// ---------------- kernel 1: RoPE tables + fp32 -> f16 pre-convert --------
// Merged launch: blocks [0,256) build the cos/sin tables; blocks [256, 3840)
// do the LDS-tile-order f16 conversion (saves one kernel launch).
// cvt dest chunk index (16B = 8 f16): ((((t*32+kt)*8+grp)*4+q)*16+l15),
// row = t*128+grp*16+l15, k = kt*32+q*8 — equals the GEMM LDS layout so
// GEMM staging is a straight dma16 copy.
#define NXCHUNK 524288    // 4096*1024/8
#define NWCHUNK 393216    // 3072*1024/8
__global__ __launch_bounds__(256) void tabcvt_k(
    const float* __restrict__ X, const float* __restrict__ W,
    unsigned short* __restrict__ Xh, unsigned short* __restrict__ Wh,
    float* __restrict__ ct, float* __restrict__ st)
{
    int bid = blockIdx.x;
    if (bid < 256) {
        int idx = bid * 256 + threadIdx.x;   // idx = s*32 + p, < 65536 exact
        int s = idx >> 5, p = idx & 31;
        double inv = pow(10000.0, -(double)(2 * p) / 64.0);
        double ang = (double)s * inv;
        ct[idx] = (float)cos(ang);
        st[idx] = (float)sin(ang);
        return;
    }
    int idx = (bid - 256) * 256 + threadIdx.x;
    const float* src;
    unsigned short* dst;
    int c;
    if (idx < NXCHUNK) { src = X; dst = Xh; c = idx; }
    else               { src = W; dst = Wh; c = idx - NXCHUNK;
                         if (c >= NWCHUNK) return; }
    int l15 = c & 15, q = (c >> 4) & 3, grp = (c >> 6) & 7;
    int kt = (c >> 9) & 31, t = c >> 14;
    int row = t * 128 + grp * 16 + l15;
    int k   = kt * 32 + q * 8;
    float4 v0 = *(const float4*)(src + (size_t)row * EE + k);
    float4 v1 = *(const float4*)(src + (size_t)row * EE + k + 4);
    *(uint4*)(dst + (size_t)c * 8) =
        make_uint4(pkh(v0.x, v0.y), pkh(v0.z, v0.w), pkh(v1.x, v1.y), pkh(v1.z, v1.w));
}

// ---------------- kernel 2: QKV GEMM (f16, dma16-staged, dbuf) -----------
// C = X @ W^T + bias. 128x128 tile, BK=32 (32 iters), 4 waves each 64x64.
// K double-buffered with prefetch + ONE barrier per K-step. XCD-pinned
// grid: each XCD owns 3 n-tiles (768 KB f16 W set in its L2). (r12 state —
// unchanged this round.)
__global__ __launch_bounds__(256, 3) void qkv_mfma_k(
    const unsigned short* __restrict__ Xh, const unsigned short* __restrict__ Wh,
    const float* __restrict__ bias,
    const float* __restrict__ ct, const float* __restrict__ st,
    unsigned short* __restrict__ Qg, unsigned short* __restrict__ Kg,
    unsigned short* __restrict__ Vg)
{
    __shared__ __align__(16) unsigned short Alds[2][4096];   // 2 x 8 KB
    __shared__ __align__(16) unsigned short Blds[2][4096];   // 2 x 8 KB

    const int tid  = threadIdx.x;
    const int wave = tid >> 6;
    const int lane = tid & 63;
    const int quad = lane >> 4;
    const int l15  = lane & 15;

    // XCD-pinned decode: 768 blocks, id&7 = XCD, 96 blocks/XCD = 3 nt x 32 mt
    const int id    = blockIdx.x;
    const int xcd   = id & 7;
    const int local = id >> 3;
    const int nt    = xcd * 3 + local % 3;
    const int mt    = local / 3;
    const int m0    = mt * 128;
    const int n0b   = nt * 128;

    f32x4 acc[4][4];
#pragma unroll
    for (int mc = 0; mc < 4; mc++)
#pragma unroll
        for (int nc = 0; nc < 4; nc++) acc[mc][nc] = (f32x4){0.f, 0.f, 0.f, 0.f};

    const int mg = (wave >> 1) * 4;
    const int ng = (wave & 1) * 4;

    // prologue: stage kt=0 into buffer 0
    {
        const unsigned short* at = Xh + ((size_t)(mt * 32)) * 4096;
        const unsigned short* bt = Wh + ((size_t)(nt * 32)) * 4096;
        dma16(at + (size_t)tid * 8,         &Alds[0][tid * 8]);
        dma16(at + (size_t)(tid + 256) * 8, &Alds[0][(tid + 256) * 8]);
        dma16(bt + (size_t)tid * 8,         &Blds[0][tid * 8]);
        dma16(bt + (size_t)(tid + 256) * 8, &Blds[0][(tid + 256) * 8]);
    }
    __syncthreads();

    int cur = 0;
    for (int kt = 0; kt < EE / 32; kt++) {
        if (kt + 1 < EE / 32) {
            const unsigned short* at = Xh + ((size_t)(mt * 32 + kt + 1)) * 4096;
            const unsigned short* bt = Wh + ((size_t)(nt * 32 + kt + 1)) * 4096;
            dma16(at + (size_t)tid * 8,         &Alds[cur ^ 1][tid * 8]);
            dma16(at + (size_t)(tid + 256) * 8, &Alds[cur ^ 1][(tid + 256) * 8]);
            dma16(bt + (size_t)tid * 8,         &Blds[cur ^ 1][tid * 8]);
            dma16(bt + (size_t)(tid + 256) * 8, &Blds[cur ^ 1][(tid + 256) * 8]);
        }

        f16x8 Af[4], Bf[4];
#pragma unroll
        for (int mc = 0; mc < 4; mc++)
            Af[mc] = *(const f16x8*)(&Alds[cur][((mg + mc) * 4 + quad) * 128 + l15 * 8]);
#pragma unroll
        for (int nc = 0; nc < 4; nc++)
            Bf[nc] = *(const f16x8*)(&Blds[cur][((ng + nc) * 4 + quad) * 128 + l15 * 8]);
#pragma unroll
        for (int mc = 0; mc < 4; mc++)
#pragma unroll
            for (int nc = 0; nc < 4; nc++)
                acc[mc][nc] = __builtin_amdgcn_mfma_f32_16x16x32_f16(Af[mc], Bf[nc], acc[mc][nc], 0, 0, 0);

        __syncthreads();   // waves done reading buf[cur]; prefetch drained
        cur ^= 1;
    }

    // ---- epilogue: bias + RoPE + f16 RNE pack + swizzled scatter ----
    const int n0w = n0b + (wave & 1) * 64;
    const int m0w = m0 + (wave >> 1) * 64;
    const int sec = n0w >> 10;
    const int h   = (n0w & 1023) >> 6;
    const int bq  = m0w >> 11;
    const size_t abase = (size_t)(bq * NHH + h) * 131072;
    unsigned short* dst = (sec == 0) ? Qg : (sec == 1) ? Kg : Vg;

    float bn[4];
#pragma unroll
    for (int nc = 0; nc < 4; nc++) bn[nc] = bias[n0w + nc * 16 + l15];

    if (sec < 2) {
        // Q gets 0.125 * log2(e) so attention softmax can use exp2 directly
        const float scq = (sec == 0) ? 0.18033688f : 1.0f;
#pragma unroll
        for (int mc = 0; mc < 4; mc++) {
            int sb = (m0w & 2047) + mc * 16;
#pragma unroll
            for (int nc = 0; nc < 4; nc++) {
                int d = nc * 16 + l15;
                int p = d >> 1;
                int kc_d = d >> 5, quad_a = (d >> 3) & 3, j = d & 7;
#pragma unroll
                for (int rr = 0; rr < 4; rr++) {
                    int srow = sb + quad * 4 + rr;
                    float x = acc[mc][nc][rr] + bn[nc];
                    float xp = __shfl_xor(x, 1);
                    float c = ct[srow * 32 + p], sn = st[srow * 32 + p];
                    float o = ((l15 & 1) == 0) ? (x * c - xp * sn) : (xp * sn + x * c);
                    o *= scq;
                    float op = __shfl_xor(o, 1);
                    if ((l15 & 1) == 0) {
                        unsigned u = pkh(o, op);   // (d, d+1) halves
                        size_t e = abase +
                            (size_t)((((srow >> 4) * 2 + kc_d) * 4 + quad_a)) * 128 +
                            (srow & 15) * 8 + j;
                        *(unsigned int*)(dst + e) = u;
                    }
                }
            }
        }
    } else {
#pragma unroll
        for (int mc = 0; mc < 4; mc++) {
            int sb = (m0w & 2047) + mc * 16;
            int s32 = sb >> 5;
            int quad_v = ((sb >> 3) + (quad >> 1)) & 3;
            int j0 = (quad & 1) * 4;
#pragma unroll
            for (int nc = 0; nc < 4; nc++) {
                float x0 = acc[mc][nc][0] + bn[nc];
                float x1 = acc[mc][nc][1] + bn[nc];
                float x2 = acc[mc][nc][2] + bn[nc];
                float x3 = acc[mc][nc][3] + bn[nc];
                unsigned u01 = pkh(x0, x1), u23 = pkh(x2, x3);
                size_t e = abase +
                    (size_t)(((s32 * 4 + nc) * 4 + quad_v)) * 128 + l15 * 8 + j0;
                *(uint2*)(dst + e) = make_uint2(u01, u23);
            }
        }
    }
}

// ---------------- kernel 3: flash attention, f16 MFMA -------------------
// r13: software-pipelined (T15 pattern). Each barrier interval issues
// QK^T MFMAs for tile kt FIRST, then runs softmax+PV for tile kt-1 while
// the matrix pipe crunches tile kt. stt consumed one interval later ->
// QK latency fully hidden under the previous tile's softmax/PV. Same
// per-tile arithmetic order as r12 -> bitwise-identical output.
__global__ __launch_bounds__(256, 4) void attn_mfma_k(
    const unsigned short* __restrict__ Qg,
    const unsigned short* __restrict__ Kg,
    const unsigned short* __restrict__ Vg,
    float* __restrict__ out)
{
    __shared__ __align__(16) unsigned short Klds[2][4096];   // K dbuf: 16 KB
    __shared__ __align__(16) unsigned short Pbuf[4][1024];   // per-wave P: 8 KB

    const int tid  = threadIdx.x;
    const int wave = tid >> 6;
    const int lane = tid & 63;
    const int quad = lane >> 4;
    const int l15  = lane & 15;
    const int id   = blockIdx.x;
    const int bh   = (id & 7) * 4 + ((id >> 3) & 3);   // XCD-pinned bh
    const int qt   = id >> 5;
    const int b    = bh >> 4, h = bh & 15;
    const int q0   = qt * 64 + wave * 16;
    const size_t abase = (size_t)bh * 131072;

    // Q fragments: 16 q rows per wave (B-operand, col = l15 = q)
    f16x8 qf[2];
#pragma unroll
    for (int kc = 0; kc < 2; kc++)
        qf[kc] = *(const f16x8*)(Qg + abase +
            (size_t)((((q0 >> 4) * 2 + kc) * 4 + quad)) * 128 + l15 * 8);

    f32x4 acc[4];
#pragma unroll
    for (int dc = 0; dc < 4; dc++) acc[dc] = (f32x4){0.f, 0.f, 0.f, 0.f};
    float mst = -INFINITY, lst = 0.f;

    const int laneoff = quad * 128 + l15 * 8;
    const unsigned short* kgb = Kg + abase;
    // per-lane V bases: vt0 covers kk2=0 (imm 0..1536B), vt1 covers kk2=1
    const unsigned short* vt0 = Vg + abase + laneoff;
    const unsigned short* vt1 = vt0 + 2048;
    unsigned short* Pw = Pbuf[wave];

    f32x4 sp[4];   // stt of the PREVIOUS tile (softmax/PV pending)

    // softmax + PV for the tile whose scores are in sp, V at vt0/vt1
    auto softmax_pv = [&]() {
        // V fragments from global (L2): imm-offset loads off two lane bases
        f16x8 vf[4][2];
#pragma unroll
        for (int dc = 0; dc < 4; dc++) {
            vf[dc][0] = *(const f16x8*)(vt0 + dc * 512);
            vf[dc][1] = *(const f16x8*)(vt1 + dc * 512);
        }

        // tile max per q-column (in-lane 16 + cross-quad shfl)
        float mt = -INFINITY;
#pragma unroll
        for (int mc = 0; mc < 4; mc++)
#pragma unroll
            for (int rr = 0; rr < 4; rr++) mt = fmaxf(mt, sp[mc][rr]);
        mt = fmaxf(mt, __shfl_xor(mt, 16));
        mt = fmaxf(mt, __shfl_xor(mt, 32));

        // defer-max: rescale only when the max grew by > 8 (exp2 domain)
        if (!__all(mt - mst <= 8.f)) {
            float mnew = fmaxf(mst, mt);
            float alpha = __builtin_amdgcn_exp2f(mst - mnew);
            lst *= alpha;
            float ar[4];
#pragma unroll
            for (int rr = 0; rr < 4; rr++)
                ar[rr] = __shfl(alpha, (lane & 48) + ((lane >> 4) << 2) + rr);
#pragma unroll
            for (int dc = 0; dc < 4; dc++)
#pragma unroll
                for (int rr = 0; rr < 4; rr++) acc[dc][rr] *= ar[rr];
            mst = mnew;
        }

        // P = exp2(S - mst) (bounded by 2^8), pack f16, scatter to Pbuf
        float ps = 0.f;
#pragma unroll
        for (int mc = 0; mc < 4; mc++) {
            float e0 = __builtin_amdgcn_exp2f(sp[mc][0] - mst);
            float e1 = __builtin_amdgcn_exp2f(sp[mc][1] - mst);
            float e2 = __builtin_amdgcn_exp2f(sp[mc][2] - mst);
            float e3 = __builtin_amdgcn_exp2f(sp[mc][3] - mst);
            ps += (e0 + e1) + (e2 + e3);
            int kk2 = mc >> 1;
            int quadp = (mc & 1) * 2 + (quad >> 1);
            int j0 = (quad & 1) * 4;
            *(uint2*)(Pw + (kk2 * 4 + quadp) * 128 + l15 * 8 + j0) =
                make_uint2(pkh(e0, e1), pkh(e2, e3));
        }
        ps += __shfl_xor(ps, 16);
        ps += __shfl_xor(ps, 32);
        lst += ps;

        f16x8 pf[2];
#pragma unroll
        for (int kk2 = 0; kk2 < 2; kk2++)
            pf[kk2] = *(const f16x8*)(Pw + (kk2 * 4 + quad) * 128 + l15 * 8);

        __builtin_amdgcn_s_setprio(1);
#pragma unroll
        for (int dc = 0; dc < 4; dc++) {
            f32x4 aa = acc[dc];
#pragma unroll
            for (int kk2 = 0; kk2 < 2; kk2++)
                aa = __builtin_amdgcn_mfma_f32_16x16x32_f16(pf[kk2], vf[dc][kk2], aa, 0, 0, 0);
            acc[dc] = aa;
        }
        __builtin_amdgcn_s_setprio(0);
    };

    // prologue: stage K tile 0
    dma16(kgb + (size_t)tid * 8,         &Klds[0][tid * 8]);
    dma16(kgb + (size_t)(tid + 256) * 8, &Klds[0][(tid + 256) * 8]);
    __syncthreads();

    int cur = 0;
    for (int kt = 0; kt < SS / 64; kt++) {
        // prefetch next K tile into the other buffer (drained at the barrier)
        if (kt + 1 < SS / 64) {
            const unsigned short* ks = kgb + (size_t)(kt + 1) * 4096;
            dma16(ks + (size_t)tid * 8,         &Klds[cur ^ 1][tid * 8]);
            dma16(ks + (size_t)(tid + 256) * 8, &Klds[cur ^ 1][(tid + 256) * 8]);
        }

        // QK^T(kt): A = K-frag (row = key), B = Q (col = q). Results are
        // consumed NEXT interval -> latency hidden under softmax_pv below.
        const unsigned short* kb = &Klds[cur][laneoff];
        f32x4 sn[4];
        __builtin_amdgcn_s_setprio(1);
#pragma unroll
        for (int mc = 0; mc < 4; mc++) {
            f16x8 a0 = *(const f16x8*)(kb + mc * 1024);
            f16x8 a1 = *(const f16x8*)(kb + mc * 1024 + 512);
            f32x4 s = (f32x4){0.f, 0.f, 0.f, 0.f};
            s = __builtin_amdgcn_mfma_f32_16x16x32_f16(a0, qf[0], s, 0, 0, 0);
            s = __builtin_amdgcn_mfma_f32_16x16x32_f16(a1, qf[1], s, 0, 0, 0);
            sn[mc] = s;
        }
        __builtin_amdgcn_s_setprio(0);

        // softmax + PV for tile kt-1 (overlaps QK^T(kt) matrix work)
        if (kt > 0) {
            softmax_pv();
            vt0 += 4096;
            vt1 += 4096;
        }

        __syncthreads();   // all waves done with Klds[cur]; prefetch drained
        cur ^= 1;
#pragma unroll
        for (int mc = 0; mc < 4; mc++) sp[mc] = sn[mc];
    }

    // epilogue: softmax + PV for the last tile (vt now points at tile 31)
    softmax_pv();

    float linv = 1.f / lst;
    float lr[4];
#pragma unroll
    for (int rr = 0; rr < 4; rr++)
        lr[rr] = __shfl(linv, (lane & 48) + ((lane >> 4) << 2) + rr);
#pragma unroll
    for (int dc = 0; dc < 4; dc++)
#pragma unroll
        for (int rr = 0; rr < 4; rr++) {
            int s = q0 + quad * 4 + rr;
            out[((size_t)(b * SS + s)) * EE + h * HD + dc * 16 + l15] = acc[dc][rr] * lr[rr];
        }
}

extern "C" void kernel_launch(void* const* d_in, const int* in_sizes, int n_in,
                              void* d_out, int out_size, void* d_ws, size_t ws_size,
                              hipStream_t stream) {
    const float* X    = (const float*)d_in[0];
    const float* W    = (const float*)d_in[1];
    const float* bias = (const float*)d_in[2];
    float* out = (float*)d_out;

    float* ws = (float*)d_ws;
    float* ct = ws;                    // 65536 f32
    float* st = ws + 65536;            // 65536 f32
    unsigned short* base = (unsigned short*)(ws + 131072);
    const size_t ASZ = (size_t)32 * 131072;   // 4.19M f16 per array
    unsigned short* Qg = base;
    unsigned short* Kg = base + ASZ;
    unsigned short* Vg = base + 2 * ASZ;
    unsigned short* Xh = base + 3 * ASZ;              // 4.19M f16 (8.4 MB)
    unsigned short* Wh = Xh + (size_t)NXCHUNK * 8;    // 3.15M f16 (6.3 MB)

    tabcvt_k<<<dim3(256 + (NXCHUNK + NWCHUNK) / 256), 256, 0, stream>>>(
        X, W, Xh, Wh, ct, st);
    qkv_mfma_k<<<dim3(768), 256, 0, stream>>>(
        Xh, Wh, bias, ct, st, Qg, Kg, Vg);
    attn_mfma_k<<<dim3(1024), 256, 0, stream>>>(Qg, Kg, Vg, out);
}

// Round 5
// 184.669 us; speedup vs baseline: 1.0308x; 1.0308x over previous
//
#include <hip/hip_runtime.h>
#include <math.h>

// Problem constants: B=2, S=2048, E=1024, NH=16, hd=64, T=1 (seq = S)
#define BB 2
#define SS 2048
#define EE 1024
#define NHH 16
#define HD 64
#define HD2 32

typedef _Float16 f16x8 __attribute__((ext_vector_type(8)));   // 8 f16 = 4 VGPRs
typedef __attribute__((ext_vector_type(4))) float f32x4;      // MFMA accumulator

// pack two fp32 -> half2 with RNE (v_cvt_f16_f32 x2 + pack)
static __device__ __forceinline__ unsigned pkh(float a, float b) {
    union { _Float16 h[2]; unsigned u; } v;
    v.h[0] = (_Float16)a; v.h[1] = (_Float16)b;
    return v.u;
}

// ---- async global->LDS DMA, 16B per lane (global_load_lds_dwordx4) ----
static __device__ __forceinline__ void dma16(const void* g, void* l) {
    __builtin_amdgcn_global_load_lds(
        (const __attribute__((address_space(1))) unsigned int*)g,
        (__attribute__((address_space(3))) unsigned int*)l,
        16, 0, 0);
}

// ---------------- kernel 1: RoPE tables + fp32 -> f16 pre-convert --------
// Merged launch: blocks [0,256) build the cos/sin tables; blocks [256, 3840)
// do the LDS-tile-order f16 conversion (saves one kernel launch).
// cvt dest chunk index (16B = 8 f16): ((((t*32+kt)*8+grp)*4+q)*16+l15),
// row = t*128+grp*16+l15, k = kt*32+q*8 — equals the GEMM LDS layout so
// GEMM staging is a straight dma16 copy.
#define NXCHUNK 524288    // 4096*1024/8
#define NWCHUNK 393216    // 3072*1024/8
__global__ __launch_bounds__(256) void tabcvt_k(
    const float* __restrict__ X, const float* __restrict__ W,
    unsigned short* __restrict__ Xh, unsigned short* __restrict__ Wh,
    float* __restrict__ ct, float* __restrict__ st)
{
    int bid = blockIdx.x;
    if (bid < 256) {
        int idx = bid * 256 + threadIdx.x;   // idx = s*32 + p, < 65536 exact
        int s = idx >> 5, p = idx & 31;
        double inv = pow(10000.0, -(double)(2 * p) / 64.0);
        double ang = (double)s * inv;
        ct[idx] = (float)cos(ang);
        st[idx] = (float)sin(ang);
        return;
    }
    int idx = (bid - 256) * 256 + threadIdx.x;
    const float* src;
    unsigned short* dst;
    int c;
    if (idx < NXCHUNK) { src = X; dst = Xh; c = idx; }
    else               { src = W; dst = Wh; c = idx - NXCHUNK;
                         if (c >= NWCHUNK) return; }
    int l15 = c & 15, q = (c >> 4) & 3, grp = (c >> 6) & 7;
    int kt = (c >> 9) & 31, t = c >> 14;
    int row = t * 128 + grp * 16 + l15;
    int k   = kt * 32 + q * 8;
    float4 v0 = *(const float4*)(src + (size_t)row * EE + k);
    float4 v1 = *(const float4*)(src + (size_t)row * EE + k + 4);
    *(uint4*)(dst + (size_t)c * 8) =
        make_uint4(pkh(v0.x, v0.y), pkh(v0.z, v0.w), pkh(v1.x, v1.y), pkh(v1.z, v1.w));
}

// ---------------- kernel 2: QKV GEMM (f16, dma16-staged, dbuf) -----------
// C = X @ W^T + bias. 128x128 tile, BK=32 (32 iters), 4 waves each 64x64.
// K double-buffered with prefetch + ONE barrier per K-step. XCD-pinned
// grid: each XCD owns 3 n-tiles (768 KB f16 W set in its L2). (r12 state —
// unchanged this round.)
__global__ __launch_bounds__(256, 3) void qkv_mfma_k(
    const unsigned short* __restrict__ Xh, const unsigned short* __restrict__ Wh,
    const float* __restrict__ bias,
    const float* __restrict__ ct, const float* __restrict__ st,
    unsigned short* __restrict__ Qg, unsigned short* __restrict__ Kg,
    unsigned short* __restrict__ Vg)
{
    __shared__ __align__(16) unsigned short Alds[2][4096];   // 2 x 8 KB
    __shared__ __align__(16) unsigned short Blds[2][4096];   // 2 x 8 KB

    const int tid  = threadIdx.x;
    const int wave = tid >> 6;
    const int lane = tid & 63;
    const int quad = lane >> 4;
    const int l15  = lane & 15;

    // XCD-pinned decode: 768 blocks, id&7 = XCD, 96 blocks/XCD = 3 nt x 32 mt
    const int id    = blockIdx.x;
    const int xcd   = id & 7;
    const int local = id >> 3;
    const int nt    = xcd * 3 + local % 3;
    const int mt    = local / 3;
    const int m0    = mt * 128;
    const int n0b   = nt * 128;

    f32x4 acc[4][4];
#pragma unroll
    for (int mc = 0; mc < 4; mc++)
#pragma unroll
        for (int nc = 0; nc < 4; nc++) acc[mc][nc] = (f32x4){0.f, 0.f, 0.f, 0.f};

    const int mg = (wave >> 1) * 4;
    const int ng = (wave & 1) * 4;

    // prologue: stage kt=0 into buffer 0
    {
        const unsigned short* at = Xh + ((size_t)(mt * 32)) * 4096;
        const unsigned short* bt = Wh + ((size_t)(nt * 32)) * 4096;
        dma16(at + (size_t)tid * 8,         &Alds[0][tid * 8]);
        dma16(at + (size_t)(tid + 256) * 8, &Alds[0][(tid + 256) * 8]);
        dma16(bt + (size_t)tid * 8,         &Blds[0][tid * 8]);
        dma16(bt + (size_t)(tid + 256) * 8, &Blds[0][(tid + 256) * 8]);
    }
    __syncthreads();

    int cur = 0;
    for (int kt = 0; kt < EE / 32; kt++) {
        if (kt + 1 < EE / 32) {
            const unsigned short* at = Xh + ((size_t)(mt * 32 + kt + 1)) * 4096;
            const unsigned short* bt = Wh + ((size_t)(nt * 32 + kt + 1)) * 4096;
            dma16(at + (size_t)tid * 8,         &Alds[cur ^ 1][tid * 8]);
            dma16(at + (size_t)(tid + 256) * 8, &Alds[cur ^ 1][(tid + 256) * 8]);
            dma16(bt + (size_t)tid * 8,         &Blds[cur ^ 1][tid * 8]);
            dma16(bt + (size_t)(tid + 256) * 8, &Blds[cur ^ 1][(tid + 256) * 8]);
        }

        f16x8 Af[4], Bf[4];
#pragma unroll
        for (int mc = 0; mc < 4; mc++)
            Af[mc] = *(const f16x8*)(&Alds[cur][((mg + mc) * 4 + quad) * 128 + l15 * 8]);
#pragma unroll
        for (int nc = 0; nc < 4; nc++)
            Bf[nc] = *(const f16x8*)(&Blds[cur][((ng + nc) * 4 + quad) * 128 + l15 * 8]);
#pragma unroll
        for (int mc = 0; mc < 4; mc++)
#pragma unroll
            for (int nc = 0; nc < 4; nc++)
                acc[mc][nc] = __builtin_amdgcn_mfma_f32_16x16x32_f16(Af[mc], Bf[nc], acc[mc][nc], 0, 0, 0);

        __syncthreads();   // waves done reading buf[cur]; prefetch drained
        cur ^= 1;
    }

    // ---- epilogue: bias + RoPE + f16 RNE pack + swizzled scatter ----
    const int n0w = n0b + (wave & 1) * 64;
    const int m0w = m0 + (wave >> 1) * 64;
    const int sec = n0w >> 10;
    const int h   = (n0w & 1023) >> 6;
    const int bq  = m0w >> 11;
    const size_t abase = (size_t)(bq * NHH + h) * 131072;
    unsigned short* dst = (sec == 0) ? Qg : (sec == 1) ? Kg : Vg;

    float bn[4];
#pragma unroll
    for (int nc = 0; nc < 4; nc++) bn[nc] = bias[n0w + nc * 16 + l15];

    if (sec < 2) {
        // Q gets 0.125 * log2(e) so attention softmax can use exp2 directly
        const float scq = (sec == 0) ? 0.18033688f : 1.0f;
#pragma unroll
        for (int mc = 0; mc < 4; mc++) {
            int sb = (m0w & 2047) + mc * 16;
#pragma unroll
            for (int nc = 0; nc < 4; nc++) {
                int d = nc * 16 + l15;
                int p = d >> 1;
                int kc_d = d >> 5, quad_a = (d >> 3) & 3, j = d & 7;
#pragma unroll
                for (int rr = 0; rr < 4; rr++) {
                    int srow = sb + quad * 4 + rr;
                    float x = acc[mc][nc][rr] + bn[nc];
                    float xp = __shfl_xor(x, 1);
                    float c = ct[srow * 32 + p], sn = st[srow * 32 + p];
                    float o = ((l15 & 1) == 0) ? (x * c - xp * sn) : (xp * sn + x * c);
                    o *= scq;
                    float op = __shfl_xor(o, 1);
                    if ((l15 & 1) == 0) {
                        unsigned u = pkh(o, op);   // (d, d+1) halves
                        size_t e = abase +
                            (size_t)((((srow >> 4) * 2 + kc_d) * 4 + quad_a)) * 128 +
                            (srow & 15) * 8 + j;
                        *(unsigned int*)(dst + e) = u;
                    }
                }
            }
        }
    } else {
#pragma unroll
        for (int mc = 0; mc < 4; mc++) {
            int sb = (m0w & 2047) + mc * 16;
            int s32 = sb >> 5;
            int quad_v = ((sb >> 3) + (quad >> 1)) & 3;
            int j0 = (quad & 1) * 4;
#pragma unroll
            for (int nc = 0; nc < 4; nc++) {
                float x0 = acc[mc][nc][0] + bn[nc];
                float x1 = acc[mc][nc][1] + bn[nc];
                float x2 = acc[mc][nc][2] + bn[nc];
                float x3 = acc[mc][nc][3] + bn[nc];
                unsigned u01 = pkh(x0, x1), u23 = pkh(x2, x3);
                size_t e = abase +
                    (size_t)(((s32 * 4 + nc) * 4 + quad_v)) * 128 + l15 * 8 + j0;
                *(uint2*)(dst + e) = make_uint2(u01, u23);
            }
        }
    }
}

// ---------------- kernel 3: flash attention, f16 MFMA -------------------
// r14: T15 reverted (r12 in-order per tile). KVBLK=128: one 16 KB K stage
// + ONE barrier per 128 keys (two identical 64-key sub-tile passes) ->
// barriers 32->16, staging/loop overhead halved per key, issue batches
// doubled. Per-64-key compute is instruction-identical to r12 -> bitwise-
// identical output. LDS 40 KB/block, still 4 blocks/CU (160 KB exactly).
__global__ __launch_bounds__(256, 4) void attn_mfma_k(
    const unsigned short* __restrict__ Qg,
    const unsigned short* __restrict__ Kg,
    const unsigned short* __restrict__ Vg,
    float* __restrict__ out)
{
    __shared__ __align__(16) unsigned short Klds[2][8192];   // K dbuf: 32 KB
    __shared__ __align__(16) unsigned short Pbuf[4][1024];   // per-wave P: 8 KB

    const int tid  = threadIdx.x;
    const int wave = tid >> 6;
    const int lane = tid & 63;
    const int quad = lane >> 4;
    const int l15  = lane & 15;
    const int id   = blockIdx.x;
    const int bh   = (id & 7) * 4 + ((id >> 3) & 3);   // XCD-pinned bh
    const int qt   = id >> 5;
    const int b    = bh >> 4, h = bh & 15;
    const int q0   = qt * 64 + wave * 16;
    const size_t abase = (size_t)bh * 131072;

    // Q fragments: 16 q rows per wave (B-operand, col = l15 = q)
    f16x8 qf[2];
#pragma unroll
    for (int kc = 0; kc < 2; kc++)
        qf[kc] = *(const f16x8*)(Qg + abase +
            (size_t)((((q0 >> 4) * 2 + kc) * 4 + quad)) * 128 + l15 * 8);

    f32x4 acc[4];
#pragma unroll
    for (int dc = 0; dc < 4; dc++) acc[dc] = (f32x4){0.f, 0.f, 0.f, 0.f};
    float mst = -INFINITY, lst = 0.f;

    const int laneoff = quad * 128 + l15 * 8;
    const unsigned short* kgb = Kg + abase;
    // per-lane V bases: vt0 covers kk2=0, vt1 covers kk2=1; advance per
    // 64-key sub-tile
    const unsigned short* vt0 = Vg + abase + laneoff;
    const unsigned short* vt1 = vt0 + 2048;
    unsigned short* Pw = Pbuf[wave];

    // one 64-key sub-tile: V load, QK^T, online softmax (defer-max), PV.
    // Identical instruction sequence to r12's per-tile body.
    auto process64 = [&](const unsigned short* ktile) {
        // V fragments from global (L2): imm-offset loads off two lane bases
        f16x8 vf[4][2];
#pragma unroll
        for (int dc = 0; dc < 4; dc++) {
            vf[dc][0] = *(const f16x8*)(vt0 + dc * 512);
            vf[dc][1] = *(const f16x8*)(vt1 + dc * 512);
        }

        // QK^T: A = K-frag (row = key), B = Q (col = q)
        const unsigned short* kb = ktile + laneoff;
        f32x4 stt[4];
        __builtin_amdgcn_s_setprio(1);
#pragma unroll
        for (int mc = 0; mc < 4; mc++) {
            f16x8 a0 = *(const f16x8*)(kb + mc * 1024);
            f16x8 a1 = *(const f16x8*)(kb + mc * 1024 + 512);
            f32x4 s = (f32x4){0.f, 0.f, 0.f, 0.f};
            s = __builtin_amdgcn_mfma_f32_16x16x32_f16(a0, qf[0], s, 0, 0, 0);
            s = __builtin_amdgcn_mfma_f32_16x16x32_f16(a1, qf[1], s, 0, 0, 0);
            stt[mc] = s;
        }
        __builtin_amdgcn_s_setprio(0);

        // tile max per q-column (in-lane 16 + cross-quad shfl)
        float mt = -INFINITY;
#pragma unroll
        for (int mc = 0; mc < 4; mc++)
#pragma unroll
            for (int rr = 0; rr < 4; rr++) mt = fmaxf(mt, stt[mc][rr]);
        mt = fmaxf(mt, __shfl_xor(mt, 16));
        mt = fmaxf(mt, __shfl_xor(mt, 32));

        // defer-max: rescale only when the max grew by > 8 (exp2 domain)
        if (!__all(mt - mst <= 8.f)) {
            float mnew = fmaxf(mst, mt);
            float alpha = __builtin_amdgcn_exp2f(mst - mnew);
            lst *= alpha;
            float ar[4];
#pragma unroll
            for (int rr = 0; rr < 4; rr++)
                ar[rr] = __shfl(alpha, (lane & 48) + ((lane >> 4) << 2) + rr);
#pragma unroll
            for (int dc = 0; dc < 4; dc++)
#pragma unroll
                for (int rr = 0; rr < 4; rr++) acc[dc][rr] *= ar[rr];
            mst = mnew;
        }

        // P = exp2(S - mst) (bounded by 2^8), pack f16, scatter to Pbuf
        float ps = 0.f;
#pragma unroll
        for (int mc = 0; mc < 4; mc++) {
            float e0 = __builtin_amdgcn_exp2f(stt[mc][0] - mst);
            float e1 = __builtin_amdgcn_exp2f(stt[mc][1] - mst);
            float e2 = __builtin_amdgcn_exp2f(stt[mc][2] - mst);
            float e3 = __builtin_amdgcn_exp2f(stt[mc][3] - mst);
            ps += (e0 + e1) + (e2 + e3);
            int kk2 = mc >> 1;
            int quadp = (mc & 1) * 2 + (quad >> 1);
            int j0 = (quad & 1) * 4;
            *(uint2*)(Pw + (kk2 * 4 + quadp) * 128 + l15 * 8 + j0) =
                make_uint2(pkh(e0, e1), pkh(e2, e3));
        }
        ps += __shfl_xor(ps, 16);
        ps += __shfl_xor(ps, 32);
        lst += ps;

        f16x8 pf[2];
#pragma unroll
        for (int kk2 = 0; kk2 < 2; kk2++)
            pf[kk2] = *(const f16x8*)(Pw + (kk2 * 4 + quad) * 128 + l15 * 8);

        __builtin_amdgcn_s_setprio(1);
#pragma unroll
        for (int dc = 0; dc < 4; dc++) {
            f32x4 aa = acc[dc];
#pragma unroll
            for (int kk2 = 0; kk2 < 2; kk2++)
                aa = __builtin_amdgcn_mfma_f32_16x16x32_f16(pf[kk2], vf[dc][kk2], aa, 0, 0, 0);
            acc[dc] = aa;
        }
        __builtin_amdgcn_s_setprio(0);

        vt0 += 4096;
        vt1 += 4096;
    };

    // prologue: stage K tile 0 (128 keys, 16 KB)
#pragma unroll
    for (int i = 0; i < 4; i++)
        dma16(kgb + (size_t)(tid + i * 256) * 8, &Klds[0][(tid + i * 256) * 8]);
    __syncthreads();

    int cur = 0;
    for (int it = 0; it < SS / 128; it++) {
        // prefetch next 128-key tile into the other buffer
        if (it + 1 < SS / 128) {
            const unsigned short* ks = kgb + (size_t)(it + 1) * 8192;
#pragma unroll
            for (int i = 0; i < 4; i++)
                dma16(ks + (size_t)(tid + i * 256) * 8,
                      &Klds[cur ^ 1][(tid + i * 256) * 8]);
        }

        process64(&Klds[cur][0]);
        process64(&Klds[cur][4096]);

        __syncthreads();   // all waves done with Klds[cur]; prefetch drained
        cur ^= 1;
    }

    float linv = 1.f / lst;
    float lr[4];
#pragma unroll
    for (int rr = 0; rr < 4; rr++)
        lr[rr] = __shfl(linv, (lane & 48) + ((lane >> 4) << 2) + rr);
#pragma unroll
    for (int dc = 0; dc < 4; dc++)
#pragma unroll
        for (int rr = 0; rr < 4; rr++) {
            int s = q0 + quad * 4 + rr;
            out[((size_t)(b * SS + s)) * EE + h * HD + dc * 16 + l15] = acc[dc][rr] * lr[rr];
        }
}

extern "C" void kernel_launch(void* const* d_in, const int* in_sizes, int n_in,
                              void* d_out, int out_size, void* d_ws, size_t ws_size,
                              hipStream_t stream) {
    const float* X    = (const float*)d_in[0];
    const float* W    = (const float*)d_in[1];
    const float* bias = (const float*)d_in[2];
    float* out = (float*)d_out;

    float* ws = (float*)d_ws;
    float* ct = ws;                    // 65536 f32
    float* st = ws + 65536;            // 65536 f32
    unsigned short* base = (unsigned short*)(ws + 131072);
    const size_t ASZ = (size_t)32 * 131072;   // 4.19M f16 per array
    unsigned short* Qg = base;
    unsigned short* Kg = base + ASZ;
    unsigned short* Vg = base + 2 * ASZ;
    unsigned short* Xh = base + 3 * ASZ;              // 4.19M f16 (8.4 MB)
    unsigned short* Wh = Xh + (size_t)NXCHUNK * 8;    // 3.15M f16 (6.3 MB)

    tabcvt_k<<<dim3(256 + (NXCHUNK + NWCHUNK) / 256), 256, 0, stream>>>(
        X, W, Xh, Wh, ct, st);
    qkv_mfma_k<<<dim3(768), 256, 0, stream>>>(
        Xh, Wh, bias, ct, st, Qg, Kg, Vg);
    attn_mfma_k<<<dim3(1024), 256, 0, stream>>>(Qg, Kg, Vg, out);
}